// Round 5
// baseline (1235.659 us; speedup 1.0000x reference)
//
#include <hip/hip_runtime.h>
#include <hip/hip_fp16.h>
#include <math.h>

#define EMB 32
#define NFEAT 128
#define RANGE 256              // nodes per bucket (dst >> 8)
#define NBUCK_MAX 512          // supports n <= 131072
#define FILL_TILE 4096         // edges per k_bfill block (16 per thread)
#define FIN_CAP 12288          // max (padded) edges per bucket staged in LDS (48 KB)
#define PAD_SLACK (RANGE * 3)  // worst-case pad growth per bucket (deg -> mult of 4)

__device__ __forceinline__ float lrelu(float z) { return z > 0.f ? z : 0.01f * z; }

// ---------------------------------------------------------------------------
// Embed: x = lrelu(nf @ W_embed + b_embed); m = lrelu(x @ W_msg + b_msg) [fp16]
// ---------------------------------------------------------------------------
__global__ __launch_bounds__(256) void k_embed(
    const float* __restrict__ nf, const float* __restrict__ Wemb,
    const float* __restrict__ bemb, const float* __restrict__ Wmsg,
    const float* __restrict__ bmsg, float* __restrict__ x,
    __half* __restrict__ m, int n)
{
    __shared__ float sW[NFEAT * EMB];   // 16 KB; sW[k*32+e]: bank==e, conflict-free
    __shared__ float sWm[EMB * EMB];    // 4 KB
    __shared__ float srow[8][NFEAT];    // 4 KB; srow[g][k] broadcast within group
    int t = threadIdx.x;
    for (int i = t; i < NFEAT * EMB; i += 256) sW[i] = Wemb[i];
    for (int i = t; i < EMB * EMB; i += 256) sWm[i] = Wmsg[i];
    __syncthreads();

    int g = t >> 5;
    int e = t & 31;
    float be = bemb[e];
    float bm = bmsg[e];

    int per_pass = gridDim.x * 8;
    int iters = (n + per_pass - 1) / per_pass;
    for (int it = 0; it < iters; ++it) {
        int node = (it * gridDim.x + blockIdx.x) * 8 + g;
        __syncthreads();
        if (node < n) {
            float4 v = ((const float4*)(nf + (size_t)node * NFEAT))[e];
            ((float4*)&srow[g][0])[e] = v;
        }
        __syncthreads();
        if (node < n) {
            float acc = be;
            #pragma unroll
            for (int k = 0; k < NFEAT; ++k)
                acc = fmaf(srow[g][k], sW[k * EMB + e], acc);
            float xv = lrelu(acc);
            x[(size_t)node * EMB + e] = xv;
            float macc = bm;
            #pragma unroll
            for (int k = 0; k < EMB; ++k)
                macc = fmaf(__shfl(xv, k, 32), sWm[k * EMB + e], macc);
            m[(size_t)node * EMB + e] = __float2half(lrelu(macc));
        }
    }
}

// ---------------------------------------------------------------------------
// Bucketed CSR build (atomic-light counting sort by dst).
// Bucket b = dst >> 8 holds edges packed as (src<<8)|(dst&255).
// ---------------------------------------------------------------------------
__global__ __launch_bounds__(256) void k_bhist(
    const int* __restrict__ dst, int* __restrict__ bucket_cnt, int E, int nbuck)
{
    __shared__ int h[NBUCK_MAX];
    int t = threadIdx.x;
    for (int i = t; i < nbuck; i += 256) h[i] = 0;
    __syncthreads();
    for (int i = blockIdx.x * 256 + t; i < E; i += gridDim.x * 256)
        atomicAdd(&h[dst[i] >> 8], 1);
    __syncthreads();
    for (int i = t; i < nbuck; i += 256)
        if (h[i]) atomicAdd(&bucket_cnt[i], h[i]);
}

__global__ __launch_bounds__(512) void k_bscan(
    const int* __restrict__ bucket_cnt, int* __restrict__ bucket_base,
    int* __restrict__ bucket_cur, int nbuck)
{
    __shared__ int s[NBUCK_MAX];
    int t = threadIdx.x;
    // region sized for worst-case deg->mult-of-4 padding, 16-int aligned
    int c = (t < nbuck) ? ((bucket_cnt[t] + PAD_SLACK + 15) & ~15) : 0;
    s[t] = c;
    __syncthreads();
    for (int off = 1; off < NBUCK_MAX; off <<= 1) {
        int add = (t >= off) ? s[t - off] : 0;
        __syncthreads();
        s[t] += add;
        __syncthreads();
    }
    if (t < nbuck) {
        int base = s[t] - c;   // exclusive
        bucket_base[t] = base;
        bucket_cur[t] = base;
    }
}

__global__ __launch_bounds__(256) void k_bfill(
    const int* __restrict__ src, const int* __restrict__ dst,
    int* __restrict__ bucket_cur, unsigned int* __restrict__ csrp, int E)
{
    __shared__ int scnt[NBUCK_MAX];
    __shared__ int gbase[NBUCK_MAX];
    int t = threadIdx.x;
    for (int i = t; i < NBUCK_MAX; i += 256) scnt[i] = 0;
    __syncthreads();

    unsigned int vals[16];
    int br[16];
    int base = blockIdx.x * FILL_TILE;
    #pragma unroll
    for (int k = 0; k < 16; ++k) {
        int e = base + k * 256 + t;
        if (e < E) {
            int d = dst[e];
            int s = src[e];
            int b = d >> 8;
            int r = atomicAdd(&scnt[b], 1);          // LDS atomic: tile-local rank
            vals[k] = ((unsigned int)s << 8) | (unsigned int)(d & 255);
            br[k] = (b << 13) | r;                    // r < 4096 fits 13 bits
        } else br[k] = -1;
    }
    __syncthreads();
    for (int i = t; i < NBUCK_MAX; i += 256) {
        int c = scnt[i];
        gbase[i] = c ? atomicAdd(&bucket_cur[i], c) : 0;  // one global atomic/bucket/tile
    }
    __syncthreads();
    #pragma unroll
    for (int k = 0; k < 16; ++k) {
        if (br[k] >= 0) {
            int b = br[k] >> 13;
            int r = br[k] & 8191;
            csrp[gbase[b] + r] = vals[k];
        }
    }
}

// One block per bucket: sort bucket's edges by dst_local fully in LDS,
// pad each node's run to a multiple of 4 with the zero-row index (zrow=n),
// emit row/pdeg, write back padded sorted src list IN PLACE.
__global__ __launch_bounds__(256) void k_csrfin(
    unsigned int* __restrict__ csrp, const int* __restrict__ bucket_base,
    const int* __restrict__ bucket_cnt, int* __restrict__ pdeg,
    int* __restrict__ row, int n, int zrow)
{
    __shared__ int lh[RANGE], pb[RANGE], lc[RANGE];
    __shared__ int ssrc[FIN_CAP];
    int bk = blockIdx.x;
    int t = threadIdx.x;
    int base = bucket_base[bk];
    int cnt = bucket_cnt[bk];
    if (cnt > FIN_CAP - PAD_SLACK) cnt = FIN_CAP - PAD_SLACK;  // safety clamp
    int node0 = bk * RANGE;

    lh[t] = 0;
    __syncthreads();
    for (int i = t; i < cnt; i += 256)
        atomicAdd(&lh[csrp[base + i] & 255], 1);
    __syncthreads();
    int h = lh[t];
    int ph = (h + 3) & ~3;              // padded degree (multiple of 4)
    pb[t] = ph;
    __syncthreads();
    for (int off = 1; off < RANGE; off <<= 1) {
        int add = (t >= off) ? pb[t - off] : 0;
        __syncthreads();
        pb[t] += add;
        __syncthreads();
    }
    int pstart = pb[t] - ph;            // exclusive prefix of padded degrees
    int node = node0 + t;
    if (node < n) {
        row[node] = base + pstart;       // 4-int aligned (base is 16-aligned)
        pdeg[node] = ph;
    }
    lc[t] = pstart;
    __syncthreads();
    for (int i = t; i < cnt; i += 256) {
        unsigned int v = csrp[base + i];
        int dl = v & 255;
        int p = atomicAdd(&lc[dl], 1);
        ssrc[p] = (int)(v >> 8);
    }
    __syncthreads();
    for (int i = h; i < ph; ++i)         // <=3 pad slots per node
        ssrc[pstart + i] = zrow;
    __syncthreads();
    int ptot = pb[RANGE - 1];
    for (int i = t; i < ptot; i += 256)
        csrp[base + i] = (unsigned int)ssrc[i];  // padded src list, dst-sorted
}

// ---------------------------------------------------------------------------
// Fused MP iteration: agg (CSR gather of fp16 rows, int4 index loads, 32-bit
// voffsets) + update GEMM + next msg (+ colsum last iter). Ping-pong m bufs.
// __launch_bounds__(256,8): 8 waves/SIMD; body sized to fit 64 VGPR w/o spill.
// ---------------------------------------------------------------------------
__global__ __launch_bounds__(256, 8) void k_mp(
    const __half* __restrict__ m_in, __half* __restrict__ m_out,
    float* __restrict__ x,
    const int* __restrict__ row_start, const int* __restrict__ pdeg,
    const int* __restrict__ csr_src,
    const float* __restrict__ Wupd, const float* __restrict__ bupd,
    const float* __restrict__ Wmsg, const float* __restrict__ bmsg,
    float* __restrict__ sums, int n, int do_msg, int do_colsum)
{
    __shared__ float sW[2 * EMB * EMB];
    __shared__ float sWm[EMB * EMB];
    __shared__ float red[8][EMB];
    int t = threadIdx.x;
    for (int i = t; i < 2 * EMB * EMB; i += 256) sW[i] = Wupd[i];
    for (int i = t; i < EMB * EMB; i += 256) sWm[i] = Wmsg[i];
    __syncthreads();

    int g = t >> 5;
    int e = t & 31;
    unsigned eu = (unsigned)e;
    float bu = bupd[e];
    float bm = bmsg[e];
    float colacc = 0.f;
    int groups = gridDim.x * 8;
    for (int node = blockIdx.x * 8 + g; node < n; node += groups) {
        const int4* cp = (const int4*)(csr_src + row_start[node]);  // 16B aligned
        int nch = pdeg[node] >> 2;
        float acc = 0.f;
        for (int c = 0; c < nch; ++c) {
            int4 ia = cp[c];
            // 32-bit voffset against uniform base -> saddr-form loads (1 VGPR each)
            float a0 = __half2float(m_in[(unsigned)ia.x * 32u + eu]);
            float a1 = __half2float(m_in[(unsigned)ia.y * 32u + eu]);
            float a2 = __half2float(m_in[(unsigned)ia.z * 32u + eu]);
            float a3 = __half2float(m_in[(unsigned)ia.w * 32u + eu]);
            acc += (a0 + a1) + (a2 + a3);
        }
        float xv = x[(size_t)node * EMB + e];
        float u = bu;
        #pragma unroll
        for (int k = 0; k < EMB; ++k)
            u = fmaf(__shfl(xv, k, 32), sW[k * EMB + e], u);
        #pragma unroll
        for (int k = 0; k < EMB; ++k)
            u = fmaf(__shfl(acc, k, 32), sW[(EMB + k) * EMB + e], u);
        float xn = lrelu(u);
        x[(size_t)node * EMB + e] = xn;
        if (do_msg) {
            float macc = bm;
            #pragma unroll
            for (int k = 0; k < EMB; ++k)
                macc = fmaf(__shfl(xn, k, 32), sWm[k * EMB + e], macc);
            m_out[(size_t)node * EMB + e] = __float2half(lrelu(macc));
        }
        if (do_colsum) colacc += xn;
    }
    if (do_colsum) {
        red[g][e] = colacc;
        __syncthreads();
        if (t < EMB) {
            float s2 = 0.f;
            #pragma unroll
            for (int gg = 0; gg < 8; ++gg) s2 += red[gg][t];
            atomicAdd(&sums[t], s2);
        }
    }
}

// ---------------------------------------------------------------------------
// Head: value = mean(x) @ W_val + b_val; probs = softmax(x[act] @ W_pol + b_pol)
// ---------------------------------------------------------------------------
__global__ __launch_bounds__(1024) void k_head(
    const float* __restrict__ x, const int* __restrict__ act,
    const float* __restrict__ Wval, const float* __restrict__ bval,
    const float* __restrict__ Wpol, const float* __restrict__ bpol,
    const float* __restrict__ sums, float* __restrict__ out, int n, int A)
{
    __shared__ float sred[64];
    int t = threadIdx.x;
    int w = t >> 6;
    int lane = t & 63;
    int nwaves = (blockDim.x + 63) >> 6;

    float logit = -INFINITY;
    if (t < A) {
        int node = act[t];
        float acc = bpol[0];
        #pragma unroll
        for (int k = 0; k < EMB; ++k)
            acc = fmaf(x[(size_t)node * EMB + k], Wpol[k], acc);
        logit = acc;
    }
    float wm = logit;
    for (int off = 32; off; off >>= 1) wm = fmaxf(wm, __shfl_xor(wm, off, 64));
    if (lane == 0) sred[w] = wm;
    __syncthreads();
    if (t == 0) {
        float mm = -INFINITY;
        for (int i = 0; i < nwaves; ++i) mm = fmaxf(mm, sred[i]);
        sred[32] = mm;
    }
    __syncthreads();
    float bmax = sred[32];
    float ex = (t < A) ? __expf(logit - bmax) : 0.f;
    float ws = ex;
    for (int off = 32; off; off >>= 1) ws += __shfl_xor(ws, off, 64);
    if (lane == 0) sred[w] = ws;
    __syncthreads();
    if (t == 0) {
        float ss = 0.f;
        for (int i = 0; i < nwaves; ++i) ss += sred[i];
        sred[33] = ss;
        float val = bval[0];
        float inv_n = 1.f / (float)n;
        #pragma unroll
        for (int k = 0; k < EMB; ++k) val = fmaf(sums[k] * inv_n, Wval[k], val);
        out[0] = val;
    }
    __syncthreads();
    float tot = sred[33];
    if (t < A) out[1 + t] = ex / tot;
}

// ---------------------------------------------------------------------------
extern "C" void kernel_launch(void* const* d_in, const int* in_sizes, int n_in,
                              void* d_out, int out_size, void* d_ws, size_t ws_size,
                              hipStream_t stream)
{
    const float* nf   = (const float*)d_in[0];
    const int*   ei   = (const int*)d_in[1];
    const int*   act  = (const int*)d_in[2];
    const float* Wemb = (const float*)d_in[3];
    const float* bemb = (const float*)d_in[4];
    const float* Wmsg = (const float*)d_in[5];
    const float* bmsg = (const float*)d_in[6];
    const float* Wupd = (const float*)d_in[7];
    const float* bupd = (const float*)d_in[8];
    const float* Wval = (const float*)d_in[9];
    const float* bval = (const float*)d_in[10];
    const float* Wpol = (const float*)d_in[11];
    const float* bpol = (const float*)d_in[12];

    int n = in_sizes[0] / NFEAT;
    int E = in_sizes[1] / 2;
    int A = in_sizes[2];
    const int* src = ei;
    const int* dst = ei + E;
    int nbuck = (n + RANGE - 1) / RANGE;          // 391 for n=100000

    char* w = (char*)d_ws;
    auto alloc = [&](size_t bytes) -> void* {
        void* p = (void*)w;
        w += (bytes + 255) & ~(size_t)255;
        return p;
    };
    float*  x    = (float*)alloc((size_t)n * EMB * 4);
    __half* mA   = (__half*)alloc((size_t)(n + 1) * EMB * 2);  // row n = zero row
    __half* mB   = (__half*)alloc((size_t)(n + 1) * EMB * 2);
    int*    pdeg = (int*)alloc((size_t)n * 4);
    int*    row  = (int*)alloc((size_t)n * 4);
    int*    bucket_cnt  = (int*)alloc((size_t)nbuck * 4);
    int*    bucket_base = (int*)alloc((size_t)nbuck * 4);
    int*    bucket_cur  = (int*)alloc((size_t)nbuck * 4);
    unsigned int* csrp  = (unsigned int*)alloc(((size_t)E + (size_t)nbuck * (PAD_SLACK + 16)) * 4);
    float*  sums = (float*)alloc(EMB * 4);

    hipMemsetAsync(bucket_cnt, 0, (size_t)nbuck * 4, stream);
    hipMemsetAsync(sums, 0, EMB * 4, stream);
    hipMemsetAsync(mA + (size_t)n * EMB, 0, EMB * 2, stream);  // zero row
    hipMemsetAsync(mB + (size_t)n * EMB, 0, EMB * 2, stream);

    const int NB = 2048;

    // embed (+ first message pass)
    k_embed<<<NB, 256, 0, stream>>>(nf, Wemb, bemb, Wmsg, bmsg, x, mA, n);

    // atomic-light CSR build (counting sort by dst, rows padded to mult of 4)
    k_bhist<<<256, 256, 0, stream>>>(dst, bucket_cnt, E, nbuck);
    k_bscan<<<1, NBUCK_MAX, 0, stream>>>(bucket_cnt, bucket_base, bucket_cur, nbuck);
    int nfill = (E + FILL_TILE - 1) / FILL_TILE;
    k_bfill<<<nfill, 256, 0, stream>>>(src, dst, bucket_cur, csrp, E);
    k_csrfin<<<nbuck, 256, 0, stream>>>(csrp, bucket_base, bucket_cnt, pdeg, row, n, n);

    // 5 fused MP iterations (ping-pong fp16 message buffers)
    __half* mi = mA;
    __half* mo = mB;
    for (int it = 0; it < 5; ++it) {
        int last = (it == 4);
        k_mp<<<NB, 256, 0, stream>>>(mi, mo, x, row, pdeg, (const int*)csrp,
                                     Wupd, bupd, Wmsg, bmsg,
                                     sums, n, last ? 0 : 1, last ? 1 : 0);
        __half* tmp = mi; mi = mo; mo = tmp;
    }

    k_head<<<1, 1024, 0, stream>>>(x, act, Wval, bval, Wpol, bpol, sums,
                                   (float*)d_out, n, A);
}

// Round 6
// 989.343 us; speedup vs baseline: 1.2490x; 1.2490x over previous
//
#include <hip/hip_runtime.h>
#include <hip/hip_fp16.h>
#include <math.h>

#define EMB 32
#define NFEAT 128
#define RANGE 256               // nodes per bucket (dst >> 8)
#define NBUCK_MAX 512           // supports n <= 131072
#define FILL_TILE 4096          // edges per k_bfill block (16 per thread)
#define FIN_CAP 12288           // max (padded) edges per bucket staged in LDS (48 KB)
#define PAD_SLACK (RANGE * 10)  // per-bucket pad growth: half0->mult8 (<=7) + half1->mult4 (<=3)

__device__ __forceinline__ float lrelu(float z) { return z > 0.f ? z : 0.01f * z; }

// ---------------------------------------------------------------------------
// Embed: x = lrelu(nf @ W_embed + b_embed); m = lrelu(x @ W_msg + b_msg) [fp16]
// ---------------------------------------------------------------------------
__global__ __launch_bounds__(256) void k_embed(
    const float* __restrict__ nf, const float* __restrict__ Wemb,
    const float* __restrict__ bemb, const float* __restrict__ Wmsg,
    const float* __restrict__ bmsg, float* __restrict__ x,
    __half* __restrict__ m, int n)
{
    __shared__ float sW[NFEAT * EMB];   // 16 KB; sW[k*32+e]: bank==e, conflict-free
    __shared__ float sWm[EMB * EMB];    // 4 KB
    __shared__ float srow[8][NFEAT];    // 4 KB
    int t = threadIdx.x;
    for (int i = t; i < NFEAT * EMB; i += 256) sW[i] = Wemb[i];
    for (int i = t; i < EMB * EMB; i += 256) sWm[i] = Wmsg[i];
    __syncthreads();

    int g = t >> 5;
    int e = t & 31;
    float be = bemb[e];
    float bm = bmsg[e];

    int per_pass = gridDim.x * 8;
    int iters = (n + per_pass - 1) / per_pass;
    for (int it = 0; it < iters; ++it) {
        int node = (it * gridDim.x + blockIdx.x) * 8 + g;
        __syncthreads();
        if (node < n) {
            float4 v = ((const float4*)(nf + (size_t)node * NFEAT))[e];
            ((float4*)&srow[g][0])[e] = v;
        }
        __syncthreads();
        if (node < n) {
            float acc = be;
            #pragma unroll
            for (int k = 0; k < NFEAT; ++k)
                acc = fmaf(srow[g][k], sW[k * EMB + e], acc);
            float xv = lrelu(acc);
            x[(size_t)node * EMB + e] = xv;
            float macc = bm;
            #pragma unroll
            for (int k = 0; k < EMB; ++k)
                macc = fmaf(__shfl(xv, k, 32), sWm[k * EMB + e], macc);
            m[(size_t)node * EMB + e] = __float2half(lrelu(macc));
        }
    }
}

// ---------------------------------------------------------------------------
// Bucketed CSR build. Bucket b = dst>>8; edges packed as (src<<8)|(dst&255).
// ---------------------------------------------------------------------------
__global__ __launch_bounds__(256) void k_bhist(
    const int* __restrict__ dst, int* __restrict__ bucket_cnt, int E, int nbuck)
{
    __shared__ int h[NBUCK_MAX];
    int t = threadIdx.x;
    for (int i = t; i < nbuck; i += 256) h[i] = 0;
    __syncthreads();
    for (int i = blockIdx.x * 256 + t; i < E; i += gridDim.x * 256)
        atomicAdd(&h[dst[i] >> 8], 1);
    __syncthreads();
    for (int i = t; i < nbuck; i += 256)
        if (h[i]) atomicAdd(&bucket_cnt[i], h[i]);
}

__global__ __launch_bounds__(512) void k_bscan(
    const int* __restrict__ bucket_cnt, int* __restrict__ bucket_base,
    int* __restrict__ bucket_cur, int nbuck)
{
    __shared__ int s[NBUCK_MAX];
    int t = threadIdx.x;
    int c = (t < nbuck) ? ((bucket_cnt[t] + PAD_SLACK + 16 + 15) & ~15) : 0;
    s[t] = c;
    __syncthreads();
    for (int off = 1; off < NBUCK_MAX; off <<= 1) {
        int add = (t >= off) ? s[t - off] : 0;
        __syncthreads();
        s[t] += add;
        __syncthreads();
    }
    if (t < nbuck) {
        int base = s[t] - c;
        bucket_base[t] = base;
        bucket_cur[t] = base;
    }
}

__global__ __launch_bounds__(256) void k_bfill(
    const int* __restrict__ src, const int* __restrict__ dst,
    int* __restrict__ bucket_cur, unsigned int* __restrict__ csrp, int E)
{
    __shared__ int scnt[NBUCK_MAX];
    __shared__ int gbase[NBUCK_MAX];
    int t = threadIdx.x;
    for (int i = t; i < NBUCK_MAX; i += 256) scnt[i] = 0;
    __syncthreads();

    unsigned int vals[16];
    int br[16];
    int base = blockIdx.x * FILL_TILE;
    #pragma unroll
    for (int k = 0; k < 16; ++k) {
        int e = base + k * 256 + t;
        if (e < E) {
            int d = dst[e];
            int s = src[e];
            int b = d >> 8;
            int r = atomicAdd(&scnt[b], 1);          // LDS atomic: tile-local rank
            vals[k] = ((unsigned int)s << 8) | (unsigned int)(d & 255);
            br[k] = (b << 13) | r;                    // r < 4096 fits 13 bits
        } else br[k] = -1;
    }
    __syncthreads();
    for (int i = t; i < NBUCK_MAX; i += 256) {
        int c = scnt[i];
        gbase[i] = c ? atomicAdd(&bucket_cur[i], c) : 0;
    }
    __syncthreads();
    #pragma unroll
    for (int k = 0; k < 16; ++k) {
        if (br[k] >= 0) {
            int b = br[k] >> 13;
            int r = br[k] & 8191;
            csrp[gbase[b] + r] = vals[k];
        }
    }
}

// One block per bucket: counting-sort the bucket's edges by key
// (dst_local, src>=half) in LDS. Half-0 sub-run padded to mult of 8,
// half-1 to mult of 4, pads = zero-row index n. Emits row (run start)
// and packed pdeg01 = p0 | (p1<<16). Writes sorted src list back IN PLACE.
__global__ __launch_bounds__(256) void k_csrfin(
    unsigned int* __restrict__ csrp, const int* __restrict__ bucket_base,
    const int* __restrict__ bucket_cnt, int* __restrict__ pdeg01,
    int* __restrict__ row, int n, int half)
{
    __shared__ int lh[2 * RANGE];      // counts per (dl, h)
    __shared__ int pst[2 * RANGE];     // padded sub-run starts
    __shared__ int lc[2 * RANGE];      // fill cursors
    __shared__ int psum[RANGE];        // per-node padded pair sums (scan)
    __shared__ int ssrc[FIN_CAP];
    int bk = blockIdx.x;
    int t = threadIdx.x;
    int base = bucket_base[bk];
    int cnt = bucket_cnt[bk];
    if (cnt > FIN_CAP - PAD_SLACK) cnt = FIN_CAP - PAD_SLACK;  // safety clamp

    lh[t] = 0;
    lh[t + RANGE] = 0;
    __syncthreads();
    for (int i = t; i < cnt; i += 256) {
        unsigned int v = csrp[base + i];
        int dl = (int)(v & 255u);
        int s = (int)(v >> 8);
        atomicAdd(&lh[dl * 2 + (s >= half ? 1 : 0)], 1);
    }
    __syncthreads();
    int c0 = lh[2 * t];
    int c1 = lh[2 * t + 1];
    int p0 = (c0 + 7) & ~7;
    int p1 = (c1 + 3) & ~3;
    psum[t] = p0 + p1;
    __syncthreads();
    for (int off = 1; off < RANGE; off <<= 1) {   // Hillis-Steele inclusive
        int add = (t >= off) ? psum[t - off] : 0;
        __syncthreads();
        psum[t] += add;
        __syncthreads();
    }
    int excl = psum[t] - (p0 + p1);
    pst[2 * t] = excl;
    pst[2 * t + 1] = excl + p0;
    lc[2 * t] = excl;
    lc[2 * t + 1] = excl + p0;
    int node = bk * RANGE + t;
    if (node < n) {
        row[node] = base + excl;                   // multiple of 4 -> uint4-aligned
        pdeg01[node] = p0 | (p1 << 16);
    }
    __syncthreads();
    for (int i = t; i < cnt; i += 256) {
        unsigned int v = csrp[base + i];
        int dl = (int)(v & 255u);
        int s = (int)(v >> 8);
        int key = dl * 2 + (s >= half ? 1 : 0);
        int p = atomicAdd(&lc[key], 1);
        ssrc[p] = s;
    }
    __syncthreads();
    for (int i = c0; i < p0; ++i) ssrc[pst[2 * t] + i] = n;      // <=7 pads
    for (int i = c1; i < p1; ++i) ssrc[pst[2 * t + 1] + i] = n;  // <=3 pads
    __syncthreads();
    int ptot = psum[RANGE - 1];
    for (int i = t; i < ptot; i += 256)
        csrp[base + i] = (unsigned int)ssrc[i];
}

// ---------------------------------------------------------------------------
// Pass A: agg[i] = sum of m rows for sub-run 0 (src < half).
// Working set = low 3.2 MB of m -> L2-resident per XCD. Chunk of 8 gathers.
// Lean body: 32-bit element offsets vs SGPR base; no launch-bounds min.
// ---------------------------------------------------------------------------
__global__ __launch_bounds__(256) void k_gather0(
    const __half* __restrict__ m_in, float* __restrict__ agg,
    const int* __restrict__ row, const int* __restrict__ pdeg01,
    const unsigned int* __restrict__ csrp, int n)
{
    int t = threadIdx.x;
    int g = t >> 5;
    unsigned eu = (unsigned)(t & 31);
    int groups = gridDim.x * 8;
    for (int node = blockIdx.x * 8 + g; node < n; node += groups) {
        const uint4* cp = (const uint4*)(csrp + row[node]);
        int nch = (pdeg01[node] & 0xffff) >> 3;
        float acc = 0.f;
        for (int c = 0; c < nch; ++c) {
            uint4 ia = cp[2 * c];
            uint4 ib = cp[2 * c + 1];
            float a0 = __half2float(m_in[ia.x * 32u + eu]);
            float a1 = __half2float(m_in[ia.y * 32u + eu]);
            float a2 = __half2float(m_in[ia.z * 32u + eu]);
            float a3 = __half2float(m_in[ia.w * 32u + eu]);
            float a4 = __half2float(m_in[ib.x * 32u + eu]);
            float a5 = __half2float(m_in[ib.y * 32u + eu]);
            float a6 = __half2float(m_in[ib.z * 32u + eu]);
            float a7 = __half2float(m_in[ib.w * 32u + eu]);
            acc += ((a0 + a1) + (a2 + a3)) + ((a4 + a5) + (a6 + a7));
        }
        agg[(unsigned)node * 32u + eu] = acc;
    }
}

// ---------------------------------------------------------------------------
// Pass B: acc = agg[i] + sum of sub-run 1 (src >= half; high 3.2 MB of m),
// then update GEMM + next message (+ colsum on last iter).
// ---------------------------------------------------------------------------
__global__ __launch_bounds__(256) void k_mp2(
    const __half* __restrict__ m_in, __half* __restrict__ m_out,
    float* __restrict__ x, const float* __restrict__ agg,
    const int* __restrict__ row, const int* __restrict__ pdeg01,
    const unsigned int* __restrict__ csrp,
    const float* __restrict__ Wupd, const float* __restrict__ bupd,
    const float* __restrict__ Wmsg, const float* __restrict__ bmsg,
    float* __restrict__ sums, int n, int do_msg, int do_colsum)
{
    __shared__ float sW[2 * EMB * EMB];
    __shared__ float sWm[EMB * EMB];
    __shared__ float red[8][EMB];
    int t = threadIdx.x;
    for (int i = t; i < 2 * EMB * EMB; i += 256) sW[i] = Wupd[i];
    for (int i = t; i < EMB * EMB; i += 256) sWm[i] = Wmsg[i];
    __syncthreads();

    int g = t >> 5;
    int e = t & 31;
    unsigned eu = (unsigned)e;
    float bu = bupd[e];
    float bm = bmsg[e];
    float colacc = 0.f;
    int groups = gridDim.x * 8;
    for (int node = blockIdx.x * 8 + g; node < n; node += groups) {
        int pd = pdeg01[node];
        const uint4* cp = (const uint4*)(csrp + row[node] + (pd & 0xffff));
        int nch = pd >> 18;                          // (p1>>2) chunks of 4
        float acc = agg[(unsigned)node * 32u + eu];
        for (int c = 0; c < nch; ++c) {
            uint4 ia = cp[c];
            float a0 = __half2float(m_in[ia.x * 32u + eu]);
            float a1 = __half2float(m_in[ia.y * 32u + eu]);
            float a2 = __half2float(m_in[ia.z * 32u + eu]);
            float a3 = __half2float(m_in[ia.w * 32u + eu]);
            acc += (a0 + a1) + (a2 + a3);
        }
        float xv = x[(size_t)node * EMB + e];
        float u = bu;
        #pragma unroll
        for (int k = 0; k < EMB; ++k)
            u = fmaf(__shfl(xv, k, 32), sW[k * EMB + e], u);
        #pragma unroll
        for (int k = 0; k < EMB; ++k)
            u = fmaf(__shfl(acc, k, 32), sW[(EMB + k) * EMB + e], u);
        float xn = lrelu(u);
        x[(size_t)node * EMB + e] = xn;
        if (do_msg) {
            float macc = bm;
            #pragma unroll
            for (int k = 0; k < EMB; ++k)
                macc = fmaf(__shfl(xn, k, 32), sWm[k * EMB + e], macc);
            m_out[(size_t)node * EMB + e] = __float2half(lrelu(macc));
        }
        if (do_colsum) colacc += xn;
    }
    if (do_colsum) {
        red[g][e] = colacc;
        __syncthreads();
        if (t < EMB) {
            float s2 = 0.f;
            #pragma unroll
            for (int gg = 0; gg < 8; ++gg) s2 += red[gg][t];
            atomicAdd(&sums[t], s2);
        }
    }
}

// ---------------------------------------------------------------------------
// Head: value = mean(x) @ W_val + b_val; probs = softmax(x[act] @ W_pol + b_pol)
// ---------------------------------------------------------------------------
__global__ __launch_bounds__(1024) void k_head(
    const float* __restrict__ x, const int* __restrict__ act,
    const float* __restrict__ Wval, const float* __restrict__ bval,
    const float* __restrict__ Wpol, const float* __restrict__ bpol,
    const float* __restrict__ sums, float* __restrict__ out, int n, int A)
{
    __shared__ float sred[64];
    int t = threadIdx.x;
    int w = t >> 6;
    int lane = t & 63;
    int nwaves = (blockDim.x + 63) >> 6;

    float logit = -INFINITY;
    if (t < A) {
        int node = act[t];
        float acc = bpol[0];
        #pragma unroll
        for (int k = 0; k < EMB; ++k)
            acc = fmaf(x[(size_t)node * EMB + k], Wpol[k], acc);
        logit = acc;
    }
    float wm = logit;
    for (int off = 32; off; off >>= 1) wm = fmaxf(wm, __shfl_xor(wm, off, 64));
    if (lane == 0) sred[w] = wm;
    __syncthreads();
    if (t == 0) {
        float mm = -INFINITY;
        for (int i = 0; i < nwaves; ++i) mm = fmaxf(mm, sred[i]);
        sred[32] = mm;
    }
    __syncthreads();
    float bmax = sred[32];
    float ex = (t < A) ? __expf(logit - bmax) : 0.f;
    float ws = ex;
    for (int off = 32; off; off >>= 1) ws += __shfl_xor(ws, off, 64);
    if (lane == 0) sred[w] = ws;
    __syncthreads();
    if (t == 0) {
        float ss = 0.f;
        for (int i = 0; i < nwaves; ++i) ss += sred[i];
        sred[33] = ss;
        float val = bval[0];
        float inv_n = 1.f / (float)n;
        #pragma unroll
        for (int k = 0; k < EMB; ++k) val = fmaf(sums[k] * inv_n, Wval[k], val);
        out[0] = val;
    }
    __syncthreads();
    float tot = sred[33];
    if (t < A) out[1 + t] = ex / tot;
}

// ---------------------------------------------------------------------------
extern "C" void kernel_launch(void* const* d_in, const int* in_sizes, int n_in,
                              void* d_out, int out_size, void* d_ws, size_t ws_size,
                              hipStream_t stream)
{
    const float* nf   = (const float*)d_in[0];
    const int*   ei   = (const int*)d_in[1];
    const int*   act  = (const int*)d_in[2];
    const float* Wemb = (const float*)d_in[3];
    const float* bemb = (const float*)d_in[4];
    const float* Wmsg = (const float*)d_in[5];
    const float* bmsg = (const float*)d_in[6];
    const float* Wupd = (const float*)d_in[7];
    const float* bupd = (const float*)d_in[8];
    const float* Wval = (const float*)d_in[9];
    const float* bval = (const float*)d_in[10];
    const float* Wpol = (const float*)d_in[11];
    const float* bpol = (const float*)d_in[12];

    int n = in_sizes[0] / NFEAT;
    int E = in_sizes[1] / 2;
    int A = in_sizes[2];
    const int* src = ei;
    const int* dst = ei + E;
    int nbuck = (n + RANGE - 1) / RANGE;          // 391 for n=100000
    int half = n / 2;

    char* w = (char*)d_ws;
    auto alloc = [&](size_t bytes) -> void* {
        void* p = (void*)w;
        w += (bytes + 255) & ~(size_t)255;
        return p;
    };
    float*  x    = (float*)alloc((size_t)n * EMB * 4);
    float*  agg  = (float*)alloc((size_t)n * EMB * 4);
    __half* mA   = (__half*)alloc((size_t)(n + 1) * EMB * 2);  // row n = zero row
    __half* mB   = (__half*)alloc((size_t)(n + 1) * EMB * 2);
    int*    pdeg01 = (int*)alloc((size_t)n * 4);
    int*    row  = (int*)alloc((size_t)n * 4);
    int*    bucket_cnt  = (int*)alloc((size_t)nbuck * 4);
    int*    bucket_base = (int*)alloc((size_t)nbuck * 4);
    int*    bucket_cur  = (int*)alloc((size_t)nbuck * 4);
    unsigned int* csrp  = (unsigned int*)alloc(((size_t)E + (size_t)nbuck * (PAD_SLACK + 32)) * 4);
    float*  sums = (float*)alloc(EMB * 4);

    hipMemsetAsync(bucket_cnt, 0, (size_t)nbuck * 4, stream);
    hipMemsetAsync(sums, 0, EMB * 4, stream);
    hipMemsetAsync(mA + (size_t)n * EMB, 0, EMB * 2, stream);  // zero row
    hipMemsetAsync(mB + (size_t)n * EMB, 0, EMB * 2, stream);

    const int NB = 2048;

    // embed (+ first message pass)
    k_embed<<<NB, 256, 0, stream>>>(nf, Wemb, bemb, Wmsg, bmsg, x, mA, n);

    // CSR build: counting sort by dst, sub-runs split by src-half
    k_bhist<<<256, 256, 0, stream>>>(dst, bucket_cnt, E, nbuck);
    k_bscan<<<1, NBUCK_MAX, 0, stream>>>(bucket_cnt, bucket_base, bucket_cur, nbuck);
    int nfill = (E + FILL_TILE - 1) / FILL_TILE;
    k_bfill<<<nfill, 256, 0, stream>>>(src, dst, bucket_cur, csrp, E);
    k_csrfin<<<nbuck, 256, 0, stream>>>(csrp, bucket_base, bucket_cnt, pdeg01, row, n, half);

    // 5 MP iterations: pass A (low-half gather) + pass B (high-half + update)
    __half* mi = mA;
    __half* mo = mB;
    for (int it = 0; it < 5; ++it) {
        int last = (it == 4);
        k_gather0<<<NB, 256, 0, stream>>>(mi, agg, row, pdeg01, csrp, n);
        k_mp2<<<NB, 256, 0, stream>>>(mi, mo, x, agg, row, pdeg01, csrp,
                                      Wupd, bupd, Wmsg, bmsg,
                                      sums, n, last ? 0 : 1, last ? 1 : 0);
        __half* tmp = mi; mi = mo; mo = tmp;
    }

    k_head<<<1, 1024, 0, stream>>>(x, act, Wval, bval, Wpol, bpol, sums,
                                   (float*)d_out, n, A);
}

// Round 7
// 682.026 us; speedup vs baseline: 1.8117x; 1.4506x over previous
//
#include <hip/hip_runtime.h>
#include <hip/hip_fp16.h>
#include <math.h>

#define EMB 32
#define NFEAT 128
#define RANGE 256               // nodes per bucket (dst >> 8)
#define NBUCK_MAX 512           // supports n <= 131072
#define FILL_TILE 4096          // edges per k_bfill block (16 per thread)
#define FIN_CAP 12288           // max (padded) edges per bucket staged in LDS (48 KB)
#define PAD_SLACK (RANGE * 10)  // per-bucket pad: half0->mult8 (<=7) + half1->mult4 (<=3)

__device__ __forceinline__ float lrelu(float z) { return z > 0.f ? z : 0.01f * z; }

// ---------------------------------------------------------------------------
// Embed: x = lrelu(nf @ W_embed + b_embed); m = lrelu(x @ W_msg + b_msg) [fp16]
// ---------------------------------------------------------------------------
__global__ __launch_bounds__(256) void k_embed(
    const float* __restrict__ nf, const float* __restrict__ Wemb,
    const float* __restrict__ bemb, const float* __restrict__ Wmsg,
    const float* __restrict__ bmsg, float* __restrict__ x,
    __half* __restrict__ m, int n)
{
    __shared__ float sW[NFEAT * EMB];   // 16 KB
    __shared__ float sWm[EMB * EMB];    // 4 KB
    __shared__ float srow[8][NFEAT];    // 4 KB
    int t = threadIdx.x;
    for (int i = t; i < NFEAT * EMB; i += 256) sW[i] = Wemb[i];
    for (int i = t; i < EMB * EMB; i += 256) sWm[i] = Wmsg[i];
    __syncthreads();

    int g = t >> 5;
    int e = t & 31;
    float be = bemb[e];
    float bm = bmsg[e];

    int per_pass = gridDim.x * 8;
    int iters = (n + per_pass - 1) / per_pass;
    for (int it = 0; it < iters; ++it) {
        int node = (it * gridDim.x + blockIdx.x) * 8 + g;
        __syncthreads();
        if (node < n) {
            float4 v = ((const float4*)(nf + (size_t)node * NFEAT))[e];
            ((float4*)&srow[g][0])[e] = v;
        }
        __syncthreads();
        if (node < n) {
            float acc = be;
            #pragma unroll
            for (int k = 0; k < NFEAT; ++k)
                acc = fmaf(srow[g][k], sW[k * EMB + e], acc);
            float xv = lrelu(acc);
            x[(size_t)node * EMB + e] = xv;
            float macc = bm;
            #pragma unroll
            for (int k = 0; k < EMB; ++k)
                macc = fmaf(__shfl(xv, k, 32), sWm[k * EMB + e], macc);
            m[(size_t)node * EMB + e] = __float2half(lrelu(macc));
        }
    }
}

// ---------------------------------------------------------------------------
// Bucketed CSR build. Bucket b = dst>>8; edges packed as (src<<8)|(dst&255).
// ---------------------------------------------------------------------------
__global__ __launch_bounds__(256) void k_bhist(
    const int* __restrict__ dst, int* __restrict__ bucket_cnt, int E, int nbuck)
{
    __shared__ int h[NBUCK_MAX];
    int t = threadIdx.x;
    for (int i = t; i < nbuck; i += 256) h[i] = 0;
    __syncthreads();
    for (int i = blockIdx.x * 256 + t; i < E; i += gridDim.x * 256)
        atomicAdd(&h[dst[i] >> 8], 1);
    __syncthreads();
    for (int i = t; i < nbuck; i += 256)
        if (h[i]) atomicAdd(&bucket_cnt[i], h[i]);
}

__global__ __launch_bounds__(512) void k_bscan(
    const int* __restrict__ bucket_cnt, int* __restrict__ bucket_base,
    int* __restrict__ bucket_cur, int nbuck)
{
    __shared__ int s[NBUCK_MAX];
    int t = threadIdx.x;
    int c = (t < nbuck) ? ((bucket_cnt[t] + PAD_SLACK + 16 + 15) & ~15) : 0;
    s[t] = c;
    __syncthreads();
    for (int off = 1; off < NBUCK_MAX; off <<= 1) {
        int add = (t >= off) ? s[t - off] : 0;
        __syncthreads();
        s[t] += add;
        __syncthreads();
    }
    if (t < nbuck) {
        int base = s[t] - c;
        bucket_base[t] = base;
        bucket_cur[t] = base;
    }
}

__global__ __launch_bounds__(256) void k_bfill(
    const int* __restrict__ src, const int* __restrict__ dst,
    int* __restrict__ bucket_cur, unsigned int* __restrict__ csrp, int E)
{
    __shared__ int scnt[NBUCK_MAX];
    __shared__ int gbase[NBUCK_MAX];
    int t = threadIdx.x;
    for (int i = t; i < NBUCK_MAX; i += 256) scnt[i] = 0;
    __syncthreads();

    unsigned int vals[16];
    int br[16];
    int base = blockIdx.x * FILL_TILE;
    #pragma unroll
    for (int k = 0; k < 16; ++k) {
        int e = base + k * 256 + t;
        if (e < E) {
            int d = dst[e];
            int s = src[e];
            int b = d >> 8;
            int r = atomicAdd(&scnt[b], 1);          // LDS atomic: tile-local rank
            vals[k] = ((unsigned int)s << 8) | (unsigned int)(d & 255);
            br[k] = (b << 13) | r;                    // r < 4096 fits 13 bits
        } else br[k] = -1;
    }
    __syncthreads();
    for (int i = t; i < NBUCK_MAX; i += 256) {
        int c = scnt[i];
        gbase[i] = c ? atomicAdd(&bucket_cur[i], c) : 0;
    }
    __syncthreads();
    #pragma unroll
    for (int k = 0; k < 16; ++k) {
        if (br[k] >= 0) {
            int b = br[k] >> 13;
            int r = br[k] & 8191;
            csrp[gbase[b] + r] = vals[k];
        }
    }
}

// One block per bucket: counting-sort by (dst_local, src>=half) in LDS.
// Half-0 run padded to mult 8, half-1 to mult 4, pads = zero-row index n.
// row = run start; pdeg01 = p0 | (p1<<16). Sorted src list written IN PLACE.
__global__ __launch_bounds__(256) void k_csrfin(
    unsigned int* __restrict__ csrp, const int* __restrict__ bucket_base,
    const int* __restrict__ bucket_cnt, int* __restrict__ pdeg01,
    int* __restrict__ row, int n, int half)
{
    __shared__ int lh[2 * RANGE];
    __shared__ int pst[2 * RANGE];
    __shared__ int lc[2 * RANGE];
    __shared__ int psum[RANGE];
    __shared__ int ssrc[FIN_CAP];
    int bk = blockIdx.x;
    int t = threadIdx.x;
    int base = bucket_base[bk];
    int cnt = bucket_cnt[bk];
    if (cnt > FIN_CAP - PAD_SLACK) cnt = FIN_CAP - PAD_SLACK;

    lh[t] = 0;
    lh[t + RANGE] = 0;
    __syncthreads();
    for (int i = t; i < cnt; i += 256) {
        unsigned int v = csrp[base + i];
        int dl = (int)(v & 255u);
        int s = (int)(v >> 8);
        atomicAdd(&lh[dl * 2 + (s >= half ? 1 : 0)], 1);
    }
    __syncthreads();
    int c0 = lh[2 * t];
    int c1 = lh[2 * t + 1];
    int p0 = (c0 + 7) & ~7;
    int p1 = (c1 + 3) & ~3;
    psum[t] = p0 + p1;
    __syncthreads();
    for (int off = 1; off < RANGE; off <<= 1) {
        int add = (t >= off) ? psum[t - off] : 0;
        __syncthreads();
        psum[t] += add;
        __syncthreads();
    }
    int excl = psum[t] - (p0 + p1);
    pst[2 * t] = excl;
    pst[2 * t + 1] = excl + p0;
    lc[2 * t] = excl;
    lc[2 * t + 1] = excl + p0;
    int node = bk * RANGE + t;
    if (node < n) {
        row[node] = base + excl;                   // mult of 4 -> uint4-aligned
        pdeg01[node] = p0 | (p1 << 16);
    }
    __syncthreads();
    for (int i = t; i < cnt; i += 256) {
        unsigned int v = csrp[base + i];
        int dl = (int)(v & 255u);
        int s = (int)(v >> 8);
        int key = dl * 2 + (s >= half ? 1 : 0);
        int p = atomicAdd(&lc[key], 1);
        ssrc[p] = s;
    }
    __syncthreads();
    for (int i = c0; i < p0; ++i) ssrc[pst[2 * t] + i] = n;
    for (int i = c1; i < p1; ++i) ssrc[pst[2 * t + 1] + i] = n;
    __syncthreads();
    int ptot = psum[RANGE - 1];
    for (int i = t; i < ptot; i += 256)
        csrp[base + i] = (unsigned int)ssrc[i];
}

// ---------------------------------------------------------------------------
// Gather pass: 16 lanes per node, each lane owns channel pair (2cp, 2cp+1).
// One load instruction covers 4 nodes per wave (4 x 64B lines in flight).
// PHASE 0: acc = sum over half-0 sub-run (low 3.2 MB of m, L2-resident),
//          writes agg. PHASE 1: RMW agg += sum over half-1 sub-run.
// No LDS, tiny body -> 8 waves/SIMD.
// ---------------------------------------------------------------------------
template<int PHASE>
__global__ __launch_bounds__(256) void k_gather(
    const __half* __restrict__ m_in, float* __restrict__ agg,
    const int* __restrict__ row, const int* __restrict__ pdeg01,
    const unsigned int* __restrict__ csrp, int n)
{
    int t = threadIdx.x;
    unsigned cp = (unsigned)(t & 15);
    int g = t >> 4;
    int groups = gridDim.x * 16;
    for (int node = blockIdx.x * 16 + g; node < n; node += groups) {
        int pd = pdeg01[node];
        int p0 = pd & 0xffff;
        float2 acc;
        if (PHASE == 0) {
            const uint4* ip = (const uint4*)(csrp + row[node]);
            int nch = p0 >> 3;               // pairs of uint4 (8 edges)
            acc.x = 0.f; acc.y = 0.f;
            for (int c = 0; c < nch; ++c) {
                uint4 ia = ip[2 * c];
                uint4 ib = ip[2 * c + 1];
                float2 f0 = __half22float2(*(const __half2*)(m_in + ia.x * 32u + 2u * cp));
                float2 f1 = __half22float2(*(const __half2*)(m_in + ia.y * 32u + 2u * cp));
                float2 f2 = __half22float2(*(const __half2*)(m_in + ia.z * 32u + 2u * cp));
                float2 f3 = __half22float2(*(const __half2*)(m_in + ia.w * 32u + 2u * cp));
                float2 f4 = __half22float2(*(const __half2*)(m_in + ib.x * 32u + 2u * cp));
                float2 f5 = __half22float2(*(const __half2*)(m_in + ib.y * 32u + 2u * cp));
                float2 f6 = __half22float2(*(const __half2*)(m_in + ib.z * 32u + 2u * cp));
                float2 f7 = __half22float2(*(const __half2*)(m_in + ib.w * 32u + 2u * cp));
                acc.x += ((f0.x + f1.x) + (f2.x + f3.x)) + ((f4.x + f5.x) + (f6.x + f7.x));
                acc.y += ((f0.y + f1.y) + (f2.y + f3.y)) + ((f4.y + f5.y) + (f6.y + f7.y));
            }
        } else {
            const uint4* ip = (const uint4*)(csrp + row[node] + p0);
            int nch = pd >> 18;              // p1>>2 chunks of 4
            acc = ((const float2*)agg)[(unsigned)node * 16u + cp];
            for (int c = 0; c < nch; ++c) {
                uint4 ia = ip[c];
                float2 f0 = __half22float2(*(const __half2*)(m_in + ia.x * 32u + 2u * cp));
                float2 f1 = __half22float2(*(const __half2*)(m_in + ia.y * 32u + 2u * cp));
                float2 f2 = __half22float2(*(const __half2*)(m_in + ia.z * 32u + 2u * cp));
                float2 f3 = __half22float2(*(const __half2*)(m_in + ia.w * 32u + 2u * cp));
                acc.x += (f0.x + f1.x) + (f2.x + f3.x);
                acc.y += (f0.y + f1.y) + (f2.y + f3.y);
            }
        }
        ((float2*)agg)[(unsigned)node * 16u + cp] = acc;
    }
}

// ---------------------------------------------------------------------------
// 16-lane-per-node GEMM helper: v is the node vector (lane cp holds channels
// 2cp, 2cp+1); W is [32][32] row-major in LDS. Returns W^T-applied pair.
// ---------------------------------------------------------------------------
__device__ __forceinline__ float2 gemm16(float2 v, const float* __restrict__ W, int cp)
{
    float2 u; u.x = 0.f; u.y = 0.f;
    #pragma unroll
    for (int kk = 0; kk < 16; ++kk) {
        float xa = __shfl(v.x, kk, 16);       // channel 2kk
        float xb = __shfl(v.y, kk, 16);       // channel 2kk+1
        float2 w0 = *(const float2*)&W[(2 * kk) * EMB + 2 * cp];
        float2 w1 = *(const float2*)&W[(2 * kk + 1) * EMB + 2 * cp];
        u.x = fmaf(xa, w0.x, u.x); u.y = fmaf(xa, w0.y, u.y);
        u.x = fmaf(xb, w1.x, u.x); u.y = fmaf(xb, w1.y, u.y);
    }
    return u;
}

// ---------------------------------------------------------------------------
// Update pass (streaming, no gathers): x = lrelu([x, agg] @ W_upd + b_upd);
// optional next message (fp16) and column-sum. 16 lanes/node, float2/lane.
// ---------------------------------------------------------------------------
template<int DO_MSG, int DO_COLSUM>
__global__ __launch_bounds__(256) void k_upd(
    float* __restrict__ x, const float* __restrict__ agg,
    __half* __restrict__ m_out,
    const float* __restrict__ Wupd, const float* __restrict__ bupd,
    const float* __restrict__ Wmsg, const float* __restrict__ bmsg,
    float* __restrict__ sums, int n)
{
    __shared__ float sW[2 * EMB * EMB];   // 8 KB
    __shared__ float sWm[EMB * EMB];      // 4 KB
    __shared__ float2 red[16][16];        // 2 KB
    int t = threadIdx.x;
    for (int i = t; i < 2 * EMB * EMB; i += 256) sW[i] = Wupd[i];
    if (DO_MSG)
        for (int i = t; i < EMB * EMB; i += 256) sWm[i] = Wmsg[i];
    __syncthreads();

    int cp = t & 15;
    int g = t >> 4;
    float2 bu = ((const float2*)bupd)[cp];
    float2 bm2;
    if (DO_MSG) bm2 = ((const float2*)bmsg)[cp];
    float2 colacc; colacc.x = 0.f; colacc.y = 0.f;
    int groups = gridDim.x * 16;
    for (int node = blockIdx.x * 16 + g; node < n; node += groups) {
        float2 x2 = ((const float2*)x)[(unsigned)node * 16u + cp];
        float2 a2 = ((const float2*)agg)[(unsigned)node * 16u + cp];
        float2 u = gemm16(x2, sW, cp);
        float2 v = gemm16(a2, sW + EMB * EMB, cp);
        float2 xn;
        xn.x = lrelu(u.x + v.x + bu.x);
        xn.y = lrelu(u.y + v.y + bu.y);
        ((float2*)x)[(unsigned)node * 16u + cp] = xn;
        if (DO_MSG) {
            float2 mm = gemm16(xn, sWm, cp);
            mm.x = lrelu(mm.x + bm2.x);
            mm.y = lrelu(mm.y + bm2.y);
            *(__half2*)(m_out + (unsigned)node * 32u + 2u * cp) = __float22half2_rn(mm);
        }
        if (DO_COLSUM) { colacc.x += xn.x; colacc.y += xn.y; }
    }
    if (DO_COLSUM) {
        red[g][cp] = colacc;
        __syncthreads();
        if (t < 16) {
            float2 s2; s2.x = 0.f; s2.y = 0.f;
            #pragma unroll
            for (int gg = 0; gg < 16; ++gg) {
                s2.x += red[gg][t].x;
                s2.y += red[gg][t].y;
            }
            atomicAdd(&sums[2 * t], s2.x);
            atomicAdd(&sums[2 * t + 1], s2.y);
        }
    }
}

// ---------------------------------------------------------------------------
// Head: value = mean(x) @ W_val + b_val; probs = softmax(x[act] @ W_pol + b_pol)
// ---------------------------------------------------------------------------
__global__ __launch_bounds__(1024) void k_head(
    const float* __restrict__ x, const int* __restrict__ act,
    const float* __restrict__ Wval, const float* __restrict__ bval,
    const float* __restrict__ Wpol, const float* __restrict__ bpol,
    const float* __restrict__ sums, float* __restrict__ out, int n, int A)
{
    __shared__ float sred[64];
    int t = threadIdx.x;
    int w = t >> 6;
    int lane = t & 63;
    int nwaves = (blockDim.x + 63) >> 6;

    float logit = -INFINITY;
    if (t < A) {
        int node = act[t];
        float acc = bpol[0];
        #pragma unroll
        for (int k = 0; k < EMB; ++k)
            acc = fmaf(x[(size_t)node * EMB + k], Wpol[k], acc);
        logit = acc;
    }
    float wm = logit;
    for (int off = 32; off; off >>= 1) wm = fmaxf(wm, __shfl_xor(wm, off, 64));
    if (lane == 0) sred[w] = wm;
    __syncthreads();
    if (t == 0) {
        float mm = -INFINITY;
        for (int i = 0; i < nwaves; ++i) mm = fmaxf(mm, sred[i]);
        sred[32] = mm;
    }
    __syncthreads();
    float bmax = sred[32];
    float ex = (t < A) ? __expf(logit - bmax) : 0.f;
    float ws = ex;
    for (int off = 32; off; off >>= 1) ws += __shfl_xor(ws, off, 64);
    if (lane == 0) sred[w] = ws;
    __syncthreads();
    if (t == 0) {
        float ss = 0.f;
        for (int i = 0; i < nwaves; ++i) ss += sred[i];
        sred[33] = ss;
        float val = bval[0];
        float inv_n = 1.f / (float)n;
        #pragma unroll
        for (int k = 0; k < EMB; ++k) val = fmaf(sums[k] * inv_n, Wval[k], val);
        out[0] = val;
    }
    __syncthreads();
    float tot = sred[33];
    if (t < A) out[1 + t] = ex / tot;
}

// ---------------------------------------------------------------------------
extern "C" void kernel_launch(void* const* d_in, const int* in_sizes, int n_in,
                              void* d_out, int out_size, void* d_ws, size_t ws_size,
                              hipStream_t stream)
{
    const float* nf   = (const float*)d_in[0];
    const int*   ei   = (const int*)d_in[1];
    const int*   act  = (const int*)d_in[2];
    const float* Wemb = (const float*)d_in[3];
    const float* bemb = (const float*)d_in[4];
    const float* Wmsg = (const float*)d_in[5];
    const float* bmsg = (const float*)d_in[6];
    const float* Wupd = (const float*)d_in[7];
    const float* bupd = (const float*)d_in[8];
    const float* Wval = (const float*)d_in[9];
    const float* bval = (const float*)d_in[10];
    const float* Wpol = (const float*)d_in[11];
    const float* bpol = (const float*)d_in[12];

    int n = in_sizes[0] / NFEAT;
    int E = in_sizes[1] / 2;
    int A = in_sizes[2];
    const int* src = ei;
    const int* dst = ei + E;
    int nbuck = (n + RANGE - 1) / RANGE;          // 391 for n=100000
    int half = n / 2;

    char* w = (char*)d_ws;
    auto alloc = [&](size_t bytes) -> void* {
        void* p = (void*)w;
        w += (bytes + 255) & ~(size_t)255;
        return p;
    };
    float*  x    = (float*)alloc((size_t)n * EMB * 4);
    float*  agg  = (float*)alloc((size_t)n * EMB * 4);
    __half* mA   = (__half*)alloc((size_t)(n + 1) * EMB * 2);  // row n = zero row
    __half* mB   = (__half*)alloc((size_t)(n + 1) * EMB * 2);
    int*    pdeg01 = (int*)alloc((size_t)n * 4);
    int*    row  = (int*)alloc((size_t)n * 4);
    int*    bucket_cnt  = (int*)alloc((size_t)nbuck * 4);
    int*    bucket_base = (int*)alloc((size_t)nbuck * 4);
    int*    bucket_cur  = (int*)alloc((size_t)nbuck * 4);
    unsigned int* csrp  = (unsigned int*)alloc(((size_t)E + (size_t)nbuck * (PAD_SLACK + 32)) * 4);
    float*  sums = (float*)alloc(EMB * 4);

    hipMemsetAsync(bucket_cnt, 0, (size_t)nbuck * 4, stream);
    hipMemsetAsync(sums, 0, EMB * 4, stream);
    hipMemsetAsync(mA + (size_t)n * EMB, 0, EMB * 2, stream);  // zero row
    hipMemsetAsync(mB + (size_t)n * EMB, 0, EMB * 2, stream);

    const int NB = 2048;

    // embed (+ first message pass)
    k_embed<<<NB, 256, 0, stream>>>(nf, Wemb, bemb, Wmsg, bmsg, x, mA, n);

    // CSR build: counting sort by dst, sub-runs split by src-half
    k_bhist<<<256, 256, 0, stream>>>(dst, bucket_cnt, E, nbuck);
    k_bscan<<<1, NBUCK_MAX, 0, stream>>>(bucket_cnt, bucket_base, bucket_cur, nbuck);
    int nfill = (E + FILL_TILE - 1) / FILL_TILE;
    k_bfill<<<nfill, 256, 0, stream>>>(src, dst, bucket_cur, csrp, E);
    k_csrfin<<<nbuck, 256, 0, stream>>>(csrp, bucket_base, bucket_cnt, pdeg01, row, n, half);

    // 5 MP iterations: gather low half, RMW high half, then streaming update
    __half* mi = mA;
    __half* mo = mB;
    for (int it = 0; it < 5; ++it) {
        k_gather<0><<<NB, 256, 0, stream>>>(mi, agg, row, pdeg01, csrp, n);
        k_gather<1><<<NB, 256, 0, stream>>>(mi, agg, row, pdeg01, csrp, n);
        if (it < 4)
            k_upd<1, 0><<<NB, 256, 0, stream>>>(x, agg, mo, Wupd, bupd, Wmsg, bmsg, sums, n);
        else
            k_upd<0, 1><<<NB, 256, 0, stream>>>(x, agg, mo, Wupd, bupd, Wmsg, bmsg, sums, n);
        __half* tmp = mi; mi = mo; mo = tmp;
    }

    k_head<<<1, 1024, 0, stream>>>(x, act, Wval, bval, Wpol, bpol, sums,
                                   (float*)d_out, n, A);
}